// Round 1
// baseline (187.064 us; speedup 1.0000x reference)
//
#include <hip/hip_runtime.h>

#define NN 512
#define DD 768
#define EPSF 1e-8f
#define TI 8
#define JCHUNK 64
#define THREADS 192

// accumulator layout in workspace (doubles):
//  acc[0] = SH  = sum_i H1[i] + sum_j H2[j]
//  acc[1] = Cd  = sum_i C[i,i]
//  acc[2] = Ct  = sum_{i,j} C[i,j]

__global__ void k_init(double* __restrict__ acc) {
    acc[0] = 0.0; acc[1] = 0.0; acc[2] = 0.0;
}

// One block per row (rows 0..511 -> z1, 512..1023 -> z2). 192 threads x float4 = 768 cols.
// Computes softmax row into p, and H = sum p*log(p+eps), atomically added into acc[0].
__global__ __launch_bounds__(THREADS) void k_softmax(
    const float* __restrict__ z1, const float* __restrict__ z2,
    float* __restrict__ p1, float* __restrict__ p2, double* __restrict__ acc) {
    __shared__ float sf[4];
    __shared__ double sd[4];
    int r = blockIdx.x;
    const float* z = (r < NN) ? (z1 + (size_t)r * DD) : (z2 + (size_t)(r - NN) * DD);
    float*       p = (r < NN) ? (p1 + (size_t)r * DD) : (p2 + (size_t)(r - NN) * DD);
    int t = threadIdx.x;
    int lane = t & 63, wid = t >> 6;

    float4 v = *(const float4*)(z + 4 * t);

    // row max
    float m = fmaxf(fmaxf(v.x, v.y), fmaxf(v.z, v.w));
    #pragma unroll
    for (int o = 32; o; o >>= 1) m = fmaxf(m, __shfl_xor(m, o, 64));
    if (lane == 0) sf[wid] = m;
    __syncthreads();
    m = fmaxf(fmaxf(sf[0], sf[1]), sf[2]);

    // exp and fp64 row sum
    float4 e;
    e.x = expf(v.x - m); e.y = expf(v.y - m);
    e.z = expf(v.z - m); e.w = expf(v.w - m);
    double s = (double)e.x + (double)e.y + (double)e.z + (double)e.w;
    #pragma unroll
    for (int o = 32; o; o >>= 1) s += __shfl_down(s, o, 64);
    if (lane == 0) sd[wid] = s;
    __syncthreads();
    float S = (float)(sd[0] + sd[1] + sd[2]);

    float4 q;
    q.x = e.x / S; q.y = e.y / S; q.z = e.z / S; q.w = e.w / S;
    *(float4*)(p + 4 * t) = q;

    // H = sum p*log(p+eps), fp64 accumulate
    double h = (double)(q.x * logf(q.x + EPSF)) + (double)(q.y * logf(q.y + EPSF))
             + (double)(q.z * logf(q.z + EPSF)) + (double)(q.w * logf(q.w + EPSF));
    __syncthreads();  // safe reuse of sd
    #pragma unroll
    for (int o = 32; o; o >>= 1) h += __shfl_down(h, o, 64);
    if (lane == 0) sd[wid] = h;
    __syncthreads();
    if (t == 0) atomicAdd(&acc[0], sd[0] + sd[1] + sd[2]);
}

// Cross-term total: block = (8 p1-rows in registers) x (64 p2-rows streamed).
// Grid (64, 8) = 512 blocks. Hot loop: 201M __logf total.
__global__ __launch_bounds__(THREADS) void k_cross(
    const float* __restrict__ p1, const float* __restrict__ p2,
    double* __restrict__ acc) {
    __shared__ double sd[4];
    int t = threadIdx.x;
    int i0 = blockIdx.x * TI;
    int j0 = blockIdx.y * JCHUNK;

    float4 a[TI];
    #pragma unroll
    for (int k = 0; k < TI; ++k)
        a[k] = *(const float4*)(p1 + (size_t)(i0 + k) * DD + 4 * t);

    double accd = 0.0;
    for (int j = j0; j < j0 + JCHUNK; ++j) {
        float4 b = *(const float4*)(p2 + (size_t)j * DD + 4 * t);
        float part = 0.0f;
        #pragma unroll
        for (int k = 0; k < TI; ++k) {
            float sx = a[k].x + b.x;
            float sy = a[k].y + b.y;
            float sz = a[k].z + b.z;
            float sw = a[k].w + b.w;
            float lx = __logf(fmaf(0.5f, sx, EPSF));
            float ly = __logf(fmaf(0.5f, sy, EPSF));
            float lz = __logf(fmaf(0.5f, sz, EPSF));
            float lw = __logf(fmaf(0.5f, sw, EPSF));
            part = fmaf(sx, lx, part);
            part = fmaf(sy, ly, part);
            part = fmaf(sz, lz, part);
            part = fmaf(sw, lw, part);
        }
        accd += (double)part;  // fp64 accumulate per (i-tile, j)
    }

    #pragma unroll
    for (int o = 32; o; o >>= 1) accd += __shfl_down(accd, o, 64);
    int lane = t & 63, wid = t >> 6;
    if (lane == 0) sd[wid] = accd;
    __syncthreads();
    if (t == 0) atomicAdd(&acc[2], sd[0] + sd[1] + sd[2]);
}

// Diagonal cross terms: one block per row i, C[i,i] -> acc[1].
__global__ __launch_bounds__(THREADS) void k_diag(
    const float* __restrict__ p1, const float* __restrict__ p2,
    double* __restrict__ acc) {
    __shared__ double sd[4];
    int i = blockIdx.x;
    int t = threadIdx.x;
    float4 a = *(const float4*)(p1 + (size_t)i * DD + 4 * t);
    float4 b = *(const float4*)(p2 + (size_t)i * DD + 4 * t);
    float sx = a.x + b.x, sy = a.y + b.y, sz = a.z + b.z, sw = a.w + b.w;
    double d = (double)(sx * logf(fmaf(0.5f, sx, EPSF)))
             + (double)(sy * logf(fmaf(0.5f, sy, EPSF)))
             + (double)(sz * logf(fmaf(0.5f, sz, EPSF)))
             + (double)(sw * logf(fmaf(0.5f, sw, EPSF)));
    #pragma unroll
    for (int o = 32; o; o >>= 1) d += __shfl_down(d, o, 64);
    int lane = t & 63, wid = t >> 6;
    if (lane == 0) sd[wid] = d;
    __syncthreads();
    if (t == 0) atomicAdd(&acc[1], sd[0] + sd[1] + sd[2]);
}

__global__ void k_final(const double* __restrict__ acc, float* __restrict__ out) {
    double SH = acc[0], Cd = acc[1], Ct = acc[2];
    double diag_sum  = 0.5 * (SH - Cd);
    double total_sum = 0.5 * ((double)NN * SH - Ct);
    double pos = diag_sum / (double)NN;
    double neg = -(total_sum - diag_sum) / ((double)NN * (double)NN - (double)NN);
    out[0] = (float)(pos + neg);
}

extern "C" void kernel_launch(void* const* d_in, const int* in_sizes, int n_in,
                              void* d_out, int out_size, void* d_ws, size_t ws_size,
                              hipStream_t stream) {
    const float* z1 = (const float*)d_in[0];
    const float* z2 = (const float*)d_in[1];
    double* acc = (double*)d_ws;
    float* p1 = (float*)((char*)d_ws + 256);
    float* p2 = p1 + (size_t)NN * DD;
    float* out = (float*)d_out;

    k_init<<<1, 1, 0, stream>>>(acc);
    k_softmax<<<2 * NN, THREADS, 0, stream>>>(z1, z2, p1, p2, acc);
    k_cross<<<dim3(NN / TI, NN / JCHUNK), THREADS, 0, stream>>>(p1, p2, acc);
    k_diag<<<NN, THREADS, 0, stream>>>(p1, p2, acc);
    k_final<<<1, 1, 0, stream>>>(acc, out);
}

// Round 2
// 122.494 us; speedup vs baseline: 1.5271x; 1.5271x over previous
//
#include <hip/hip_runtime.h>

#define NN 512
#define DD 768
#define EPSF 1e-8f
#define TI 8
#define JCHUNK 16
#define THREADS 192
#define LN2 0.6931471805599453

// accumulator layout in workspace (doubles):
//  acc[0] = SHl2 = sum_i H1[i] + sum_j H2[j]      (in log2 units)
//  acc[1] = Cdl2 = sum_i C[i,i]                    (in log2 units)
//  acc[2] = Ctl2 = sum_{i,j} C[i,j]                (in log2 units)

// One block per row (rows 0..511 -> z1, 512..1023 -> z2). 192 threads x float4 = 768 cols.
__global__ __launch_bounds__(THREADS) void k_softmax(
    const float* __restrict__ z1, const float* __restrict__ z2,
    float* __restrict__ p1, float* __restrict__ p2, double* __restrict__ acc) {
    __shared__ float sf[4];
    __shared__ double sd[4];
    int r = blockIdx.x;
    const float* z = (r < NN) ? (z1 + (size_t)r * DD) : (z2 + (size_t)(r - NN) * DD);
    float*       p = (r < NN) ? (p1 + (size_t)r * DD) : (p2 + (size_t)(r - NN) * DD);
    int t = threadIdx.x;
    int lane = t & 63, wid = t >> 6;

    float4 v = *(const float4*)(z + 4 * t);

    // row max
    float m = fmaxf(fmaxf(v.x, v.y), fmaxf(v.z, v.w));
    #pragma unroll
    for (int o = 32; o; o >>= 1) m = fmaxf(m, __shfl_xor(m, o, 64));
    if (lane == 0) sf[wid] = m;
    __syncthreads();
    m = fmaxf(fmaxf(sf[0], sf[1]), sf[2]);

    // exp and fp64 row sum
    float4 e;
    e.x = __expf(v.x - m); e.y = __expf(v.y - m);
    e.z = __expf(v.z - m); e.w = __expf(v.w - m);
    double s = (double)e.x + (double)e.y + (double)e.z + (double)e.w;
    #pragma unroll
    for (int o = 32; o; o >>= 1) s += __shfl_down(s, o, 64);
    if (lane == 0) sd[wid] = s;
    __syncthreads();
    float S = (float)(sd[0] + sd[1] + sd[2]);
    float invS = 1.0f / S;

    float4 q;
    q.x = e.x * invS; q.y = e.y * invS; q.z = e.z * invS; q.w = e.w * invS;
    *(float4*)(p + 4 * t) = q;

    // H (log2 units) = sum p*log2(p+eps), fp64 accumulate
    double h = (double)(q.x * __log2f(q.x + EPSF)) + (double)(q.y * __log2f(q.y + EPSF))
             + (double)(q.z * __log2f(q.z + EPSF)) + (double)(q.w * __log2f(q.w + EPSF));
    __syncthreads();  // safe reuse of sd
    #pragma unroll
    for (int o = 32; o; o >>= 1) h += __shfl_down(h, o, 64);
    if (lane == 0) sd[wid] = h;
    __syncthreads();
    if (t == 0) atomicAdd(&acc[0], sd[0] + sd[1] + sd[2]);
}

// Cross-term total (log2 units): block = (8 p1-rows in registers) x (16 p2-rows streamed).
// Grid (64, 32) = 2048 blocks = ~8 blocks/CU -> high occupancy.
// Inner element: s=a+b; t=fma(0.5,a,bh); l=v_log_f32(t); part=fma(s,l,part)  -> 4 issues + 1 trans
__global__ __launch_bounds__(THREADS) void k_cross(
    const float* __restrict__ p1, const float* __restrict__ p2,
    double* __restrict__ acc) {
    __shared__ double sd[4];
    int t = threadIdx.x;
    int i0 = blockIdx.x * TI;
    int j0 = blockIdx.y * JCHUNK;

    float4 a[TI];
    #pragma unroll
    for (int k = 0; k < TI; ++k)
        a[k] = *(const float4*)(p1 + (size_t)(i0 + k) * DD + 4 * t);

    double accd = 0.0;
    for (int j = j0; j < j0 + JCHUNK; ++j) {
        float4 b = *(const float4*)(p2 + (size_t)j * DD + 4 * t);
        float4 bh;
        bh.x = fmaf(0.5f, b.x, EPSF);
        bh.y = fmaf(0.5f, b.y, EPSF);
        bh.z = fmaf(0.5f, b.z, EPSF);
        bh.w = fmaf(0.5f, b.w, EPSF);
        float part = 0.0f;
        #pragma unroll
        for (int k = 0; k < TI; ++k) {
            float sx = a[k].x + b.x;
            float sy = a[k].y + b.y;
            float sz = a[k].z + b.z;
            float sw = a[k].w + b.w;
            float lx = __log2f(fmaf(0.5f, a[k].x, bh.x));
            float ly = __log2f(fmaf(0.5f, a[k].y, bh.y));
            float lz = __log2f(fmaf(0.5f, a[k].z, bh.z));
            float lw = __log2f(fmaf(0.5f, a[k].w, bh.w));
            part = fmaf(sx, lx, part);
            part = fmaf(sy, ly, part);
            part = fmaf(sz, lz, part);
            part = fmaf(sw, lw, part);
        }
        accd += (double)part;  // fp64 accumulate per (i-tile, j)
    }

    #pragma unroll
    for (int o = 32; o; o >>= 1) accd += __shfl_down(accd, o, 64);
    int lane = t & 63, wid = t >> 6;
    if (lane == 0) sd[wid] = accd;
    __syncthreads();
    if (t == 0) atomicAdd(&acc[2], sd[0] + sd[1] + sd[2]);
}

// Diagonal cross terms (log2 units): one block per row i -> acc[1].
__global__ __launch_bounds__(THREADS) void k_diag(
    const float* __restrict__ p1, const float* __restrict__ p2,
    double* __restrict__ acc) {
    __shared__ double sd[4];
    int i = blockIdx.x;
    int t = threadIdx.x;
    float4 a = *(const float4*)(p1 + (size_t)i * DD + 4 * t);
    float4 b = *(const float4*)(p2 + (size_t)i * DD + 4 * t);
    float sx = a.x + b.x, sy = a.y + b.y, sz = a.z + b.z, sw = a.w + b.w;
    double d = (double)(sx * __log2f(fmaf(0.5f, sx, EPSF)))
             + (double)(sy * __log2f(fmaf(0.5f, sy, EPSF)))
             + (double)(sz * __log2f(fmaf(0.5f, sz, EPSF)))
             + (double)(sw * __log2f(fmaf(0.5f, sw, EPSF)));
    #pragma unroll
    for (int o = 32; o; o >>= 1) d += __shfl_down(d, o, 64);
    int lane = t & 63, wid = t >> 6;
    if (lane == 0) sd[wid] = d;
    __syncthreads();
    if (t == 0) atomicAdd(&acc[1], sd[0] + sd[1] + sd[2]);
}

__global__ void k_final(const double* __restrict__ acc, float* __restrict__ out) {
    double SH = acc[0] * LN2, Cd = acc[1] * LN2, Ct = acc[2] * LN2;
    double diag_sum  = 0.5 * (SH - Cd);
    double total_sum = 0.5 * ((double)NN * SH - Ct);
    double pos = diag_sum / (double)NN;
    double neg = -(total_sum - diag_sum) / ((double)NN * (double)NN - (double)NN);
    out[0] = (float)(pos + neg);
}

extern "C" void kernel_launch(void* const* d_in, const int* in_sizes, int n_in,
                              void* d_out, int out_size, void* d_ws, size_t ws_size,
                              hipStream_t stream) {
    const float* z1 = (const float*)d_in[0];
    const float* z2 = (const float*)d_in[1];
    double* acc = (double*)d_ws;
    float* p1 = (float*)((char*)d_ws + 256);
    float* p2 = p1 + (size_t)NN * DD;
    float* out = (float*)d_out;

    hipMemsetAsync(acc, 0, 3 * sizeof(double), stream);
    k_softmax<<<2 * NN, THREADS, 0, stream>>>(z1, z2, p1, p2, acc);
    k_cross<<<dim3(NN / TI, NN / JCHUNK), THREADS, 0, stream>>>(p1, p2, acc);
    k_diag<<<NN, THREADS, 0, stream>>>(p1, p2, acc);
    k_final<<<1, 1, 0, stream>>>(acc, out);
}

// Round 3
// 93.174 us; speedup vs baseline: 2.0077x; 1.3147x over previous
//
#include <hip/hip_runtime.h>

#define NN 512
#define DD 768
#define EPSF 1e-8f
#define TI 8
#define JCHUNK 16
#define JBLK (NN / JCHUNK)   // 32
#define IBLK (NN / TI)       // 64
#define THREADS 192
#define LN2 0.6931471805599453

// ws layout (bytes):
//   hrow  @ 0      : 1024 doubles (per-row H, log2 units)
//   cpart @ 8192   : IBLK*JBLK = 2048 doubles (cross partials, log2 units)
//   dpart @ 24576  : IBLK = 64 doubles (diag partials, log2 units)
//   p1    @ 32768  : 512*768 floats
//   p2    after p1

// One block per row (rows 0..511 -> z1, 512..1023 -> z2). 192 threads x float4.
__global__ __launch_bounds__(THREADS) void k_softmax(
    const float* __restrict__ z1, const float* __restrict__ z2,
    float* __restrict__ p1, float* __restrict__ p2, double* __restrict__ hrow) {
    __shared__ float sf[4];
    __shared__ double sd[4];
    int r = blockIdx.x;
    const float* z = (r < NN) ? (z1 + (size_t)r * DD) : (z2 + (size_t)(r - NN) * DD);
    float*       p = (r < NN) ? (p1 + (size_t)r * DD) : (p2 + (size_t)(r - NN) * DD);
    int t = threadIdx.x;
    int lane = t & 63, wid = t >> 6;

    float4 v = *(const float4*)(z + 4 * t);

    float m = fmaxf(fmaxf(v.x, v.y), fmaxf(v.z, v.w));
    #pragma unroll
    for (int o = 32; o; o >>= 1) m = fmaxf(m, __shfl_xor(m, o, 64));
    if (lane == 0) sf[wid] = m;
    __syncthreads();
    m = fmaxf(fmaxf(sf[0], sf[1]), sf[2]);

    float4 e;
    e.x = __expf(v.x - m); e.y = __expf(v.y - m);
    e.z = __expf(v.z - m); e.w = __expf(v.w - m);
    double s = (double)e.x + (double)e.y + (double)e.z + (double)e.w;
    #pragma unroll
    for (int o = 32; o; o >>= 1) s += __shfl_down(s, o, 64);
    if (lane == 0) sd[wid] = s;
    __syncthreads();
    float S = (float)(sd[0] + sd[1] + sd[2]);
    float invS = 1.0f / S;

    float4 q;
    q.x = e.x * invS; q.y = e.y * invS; q.z = e.z * invS; q.w = e.w * invS;
    *(float4*)(p + 4 * t) = q;

    double h = (double)(q.x * __log2f(q.x + EPSF)) + (double)(q.y * __log2f(q.y + EPSF))
             + (double)(q.z * __log2f(q.z + EPSF)) + (double)(q.w * __log2f(q.w + EPSF));
    __syncthreads();
    #pragma unroll
    for (int o = 32; o; o >>= 1) h += __shfl_down(h, o, 64);
    if (lane == 0) sd[wid] = h;
    __syncthreads();
    if (t == 0) hrow[r] = sd[0] + sd[1] + sd[2];
}

// Cross partials (log2 units). grid = (IBLK, JBLK+1); y==JBLK rows do the diagonal.
// a-tile pinned in 8 named float4 regs; b double-buffered.
__global__ __launch_bounds__(THREADS, 6) void k_cross(
    const float* __restrict__ p1, const float* __restrict__ p2,
    double* __restrict__ cpart, double* __restrict__ dpart) {
    __shared__ double sd[4];
    int t = threadIdx.x;
    int bx = blockIdx.x;
    int by = blockIdx.y;
    int lane = t & 63, wid = t >> 6;
    double accd = 0.0;

    if (by < JBLK) {
        const float* ap = p1 + (size_t)bx * TI * DD + 4 * t;
        float4 a0 = *(const float4*)(ap + 0 * DD);
        float4 a1 = *(const float4*)(ap + 1 * DD);
        float4 a2 = *(const float4*)(ap + 2 * DD);
        float4 a3 = *(const float4*)(ap + 3 * DD);
        float4 a4 = *(const float4*)(ap + 4 * DD);
        float4 a5 = *(const float4*)(ap + 5 * DD);
        float4 a6 = *(const float4*)(ap + 6 * DD);
        float4 a7 = *(const float4*)(ap + 7 * DD);

        const float* bp = p2 + (size_t)by * JCHUNK * DD + 4 * t;
        float4 b = *(const float4*)bp;
        for (int j = 0; j < JCHUNK; ++j) {
            float4 bn = (j + 1 < JCHUNK) ? *(const float4*)(bp + (size_t)(j + 1) * DD) : b;
            float part = 0.0f;
            #define ELT(A) { \
                float sx = A.x + b.x, sy = A.y + b.y, sz = A.z + b.z, sw = A.w + b.w; \
                part = fmaf(sx, __log2f(fmaf(0.5f, sx, EPSF)), part); \
                part = fmaf(sy, __log2f(fmaf(0.5f, sy, EPSF)), part); \
                part = fmaf(sz, __log2f(fmaf(0.5f, sz, EPSF)), part); \
                part = fmaf(sw, __log2f(fmaf(0.5f, sw, EPSF)), part); }
            ELT(a0) ELT(a1) ELT(a2) ELT(a3) ELT(a4) ELT(a5) ELT(a6) ELT(a7)
            #undef ELT
            accd += (double)part;
            b = bn;
        }
    } else {
        #pragma unroll
        for (int k = 0; k < TI; ++k) {
            int i = bx * TI + k;
            float4 a = *(const float4*)(p1 + (size_t)i * DD + 4 * t);
            float4 b = *(const float4*)(p2 + (size_t)i * DD + 4 * t);
            float sx = a.x + b.x, sy = a.y + b.y, sz = a.z + b.z, sw = a.w + b.w;
            float part = 0.0f;
            part = fmaf(sx, __log2f(fmaf(0.5f, sx, EPSF)), part);
            part = fmaf(sy, __log2f(fmaf(0.5f, sy, EPSF)), part);
            part = fmaf(sz, __log2f(fmaf(0.5f, sz, EPSF)), part);
            part = fmaf(sw, __log2f(fmaf(0.5f, sw, EPSF)), part);
            accd += (double)part;
        }
    }

    #pragma unroll
    for (int o = 32; o; o >>= 1) accd += __shfl_down(accd, o, 64);
    if (lane == 0) sd[wid] = accd;
    __syncthreads();
    if (t == 0) {
        double v = sd[0] + sd[1] + sd[2];
        if (by < JBLK) cpart[by * IBLK + bx] = v;
        else           dpart[bx] = v;
    }
}

__global__ __launch_bounds__(256) void k_final(
    const double* __restrict__ hrow, const double* __restrict__ cpart,
    const double* __restrict__ dpart, float* __restrict__ out) {
    __shared__ double sh[4], sc[4], sg[4];
    int t = threadIdx.x, lane = t & 63, wid = t >> 6;
    double h = 0.0, c = 0.0, d = 0.0;
    for (int i = t; i < 2 * NN; i += 256) h += hrow[i];
    for (int i = t; i < IBLK * JBLK; i += 256) c += cpart[i];
    if (t < IBLK) d = dpart[t];
    #pragma unroll
    for (int o = 32; o; o >>= 1) {
        h += __shfl_down(h, o, 64);
        c += __shfl_down(c, o, 64);
        d += __shfl_down(d, o, 64);
    }
    if (lane == 0) { sh[wid] = h; sc[wid] = c; sg[wid] = d; }
    __syncthreads();
    if (t == 0) {
        double SH = (sh[0] + sh[1] + sh[2] + sh[3]) * LN2;
        double Ct = (sc[0] + sc[1] + sc[2] + sc[3]) * LN2;
        double Cd = (sg[0] + sg[1] + sg[2] + sg[3]) * LN2;
        double diag_sum  = 0.5 * (SH - Cd);
        double total_sum = 0.5 * ((double)NN * SH - Ct);
        double pos = diag_sum / (double)NN;
        double neg = -(total_sum - diag_sum) / ((double)NN * (double)NN - (double)NN);
        out[0] = (float)(pos + neg);
    }
}

extern "C" void kernel_launch(void* const* d_in, const int* in_sizes, int n_in,
                              void* d_out, int out_size, void* d_ws, size_t ws_size,
                              hipStream_t stream) {
    const float* z1 = (const float*)d_in[0];
    const float* z2 = (const float*)d_in[1];
    char* ws = (char*)d_ws;
    double* hrow  = (double*)(ws);
    double* cpart = (double*)(ws + 8192);
    double* dpart = (double*)(ws + 24576);
    float*  p1    = (float*)(ws + 32768);
    float*  p2    = p1 + (size_t)NN * DD;
    float* out = (float*)d_out;

    k_softmax<<<2 * NN, THREADS, 0, stream>>>(z1, z2, p1, p2, hrow);
    k_cross<<<dim3(IBLK, JBLK + 1), THREADS, 0, stream>>>(p1, p2, cpart, dpart);
    k_final<<<1, 256, 0, stream>>>(hrow, cpart, dpart, out);
}

// Round 4
// 87.730 us; speedup vs baseline: 2.1323x; 1.0620x over previous
//
#include <hip/hip_runtime.h>

#define NN 512
#define DD 768
#define EPSF 1e-8f
#define TI 8
#define JCHUNK 16
#define JBLK (NN / JCHUNK)   // 32
#define IBLK (NN / TI)       // 64
#define THREADS 192
#define LN2 0.6931471805599453

// ws layout (bytes):
//   hrow  @ 0      : 1024 doubles (per-row H, log2 units)
//   cpart @ 8192   : IBLK*JBLK = 2048 doubles (cross partials, raw sum s*log2(s))
//   dpart @ 24576  : IBLK = 64 doubles (diag partials, exact-eps, log2 units)
//   p1    @ 32768  : 512*768 floats
//   p2    after p1
//
// Cross identity:  sum_d s*log2(s/2+eps)
//                = sum_d s*log2(s) - sum_d s + sum_d s*log2(1+2eps/s)
//   sum over all (i,j): sum s = 2*N^2 exactly; eps term -> 2*EPS*D*N^2/ln2
//   (deterministic to O(eps^2/s), ~1e-10 in the output). Folded into k_final.

// One block per row (rows 0..511 -> z1, 512..1023 -> z2). 192 threads x float4.
__global__ __launch_bounds__(THREADS) void k_softmax(
    const float* __restrict__ z1, const float* __restrict__ z2,
    float* __restrict__ p1, float* __restrict__ p2, double* __restrict__ hrow) {
    __shared__ float sf[4];
    __shared__ double sd[4];
    int r = blockIdx.x;
    const float* z = (r < NN) ? (z1 + (size_t)r * DD) : (z2 + (size_t)(r - NN) * DD);
    float*       p = (r < NN) ? (p1 + (size_t)r * DD) : (p2 + (size_t)(r - NN) * DD);
    int t = threadIdx.x;
    int lane = t & 63, wid = t >> 6;

    float4 v = *(const float4*)(z + 4 * t);

    float m = fmaxf(fmaxf(v.x, v.y), fmaxf(v.z, v.w));
    #pragma unroll
    for (int o = 32; o; o >>= 1) m = fmaxf(m, __shfl_xor(m, o, 64));
    if (lane == 0) sf[wid] = m;
    __syncthreads();
    m = fmaxf(fmaxf(sf[0], sf[1]), sf[2]);

    float4 e;
    e.x = __expf(v.x - m); e.y = __expf(v.y - m);
    e.z = __expf(v.z - m); e.w = __expf(v.w - m);
    double s = (double)e.x + (double)e.y + (double)e.z + (double)e.w;
    #pragma unroll
    for (int o = 32; o; o >>= 1) s += __shfl_down(s, o, 64);
    if (lane == 0) sd[wid] = s;
    __syncthreads();
    float S = (float)(sd[0] + sd[1] + sd[2]);
    float invS = 1.0f / S;

    float4 q;
    q.x = e.x * invS; q.y = e.y * invS; q.z = e.z * invS; q.w = e.w * invS;
    *(float4*)(p + 4 * t) = q;

    double h = (double)(q.x * __log2f(q.x + EPSF)) + (double)(q.y * __log2f(q.y + EPSF))
             + (double)(q.z * __log2f(q.z + EPSF)) + (double)(q.w * __log2f(q.w + EPSF));
    __syncthreads();
    #pragma unroll
    for (int o = 32; o; o >>= 1) h += __shfl_down(h, o, 64);
    if (lane == 0) sd[wid] = h;
    __syncthreads();
    if (t == 0) hrow[r] = sd[0] + sd[1] + sd[2];
}

// Cross partials: raw sum of s*log2(s) (eps + "-sum s" handled analytically in k_final).
// grid = (IBLK, JBLK+1); y==JBLK rows do the exact-eps diagonal.
// Inner element: s=a+b (VALU), l=v_log_f32(s) (trans), part=fma(s,l,part) (VALU).
__global__ __launch_bounds__(THREADS, 6) void k_cross(
    const float* __restrict__ p1, const float* __restrict__ p2,
    double* __restrict__ cpart, double* __restrict__ dpart) {
    __shared__ double sd[4];
    int t = threadIdx.x;
    int bx = blockIdx.x;
    int by = blockIdx.y;
    int lane = t & 63, wid = t >> 6;
    double accd = 0.0;

    if (by < JBLK) {
        const float* ap = p1 + (size_t)bx * TI * DD + 4 * t;
        float4 a0 = *(const float4*)(ap + 0 * DD);
        float4 a1 = *(const float4*)(ap + 1 * DD);
        float4 a2 = *(const float4*)(ap + 2 * DD);
        float4 a3 = *(const float4*)(ap + 3 * DD);
        float4 a4 = *(const float4*)(ap + 4 * DD);
        float4 a5 = *(const float4*)(ap + 5 * DD);
        float4 a6 = *(const float4*)(ap + 6 * DD);
        float4 a7 = *(const float4*)(ap + 7 * DD);

        const float* bp = p2 + (size_t)by * JCHUNK * DD + 4 * t;
        float4 b = *(const float4*)bp;
        for (int j = 0; j < JCHUNK; ++j) {
            float4 bn = (j + 1 < JCHUNK) ? *(const float4*)(bp + (size_t)(j + 1) * DD) : b;
            float part = 0.0f;
            #define ELT(A) { \
                float sx = A.x + b.x, sy = A.y + b.y, sz = A.z + b.z, sw = A.w + b.w; \
                part = fmaf(sx, __log2f(sx), part); \
                part = fmaf(sy, __log2f(sy), part); \
                part = fmaf(sz, __log2f(sz), part); \
                part = fmaf(sw, __log2f(sw), part); }
            ELT(a0) ELT(a1) ELT(a2) ELT(a3) ELT(a4) ELT(a5) ELT(a6) ELT(a7)
            #undef ELT
            accd += (double)part;
            b = bn;
        }
    } else {
        #pragma unroll
        for (int k = 0; k < TI; ++k) {
            int i = bx * TI + k;
            float4 a = *(const float4*)(p1 + (size_t)i * DD + 4 * t);
            float4 b = *(const float4*)(p2 + (size_t)i * DD + 4 * t);
            float sx = a.x + b.x, sy = a.y + b.y, sz = a.z + b.z, sw = a.w + b.w;
            float part = 0.0f;
            part = fmaf(sx, __log2f(fmaf(0.5f, sx, EPSF)), part);
            part = fmaf(sy, __log2f(fmaf(0.5f, sy, EPSF)), part);
            part = fmaf(sz, __log2f(fmaf(0.5f, sz, EPSF)), part);
            part = fmaf(sw, __log2f(fmaf(0.5f, sw, EPSF)), part);
            accd += (double)part;
        }
    }

    #pragma unroll
    for (int o = 32; o; o >>= 1) accd += __shfl_down(accd, o, 64);
    if (lane == 0) sd[wid] = accd;
    __syncthreads();
    if (t == 0) {
        double v = sd[0] + sd[1] + sd[2];
        if (by < JBLK) cpart[by * IBLK + bx] = v;
        else           dpart[bx] = v;
    }
}

__global__ __launch_bounds__(256) void k_final(
    const double* __restrict__ hrow, const double* __restrict__ cpart,
    const double* __restrict__ dpart, float* __restrict__ out) {
    __shared__ double sh[4], sc[4], sg[4];
    int t = threadIdx.x, lane = t & 63, wid = t >> 6;
    double h = 0.0, c = 0.0, d = 0.0;
    for (int i = t; i < 2 * NN; i += 256) h += hrow[i];
    for (int i = t; i < IBLK * JBLK; i += 256) c += cpart[i];
    if (t < IBLK) d = dpart[t];
    #pragma unroll
    for (int o = 32; o; o >>= 1) {
        h += __shfl_down(h, o, 64);
        c += __shfl_down(c, o, 64);
        d += __shfl_down(d, o, 64);
    }
    if (lane == 0) { sh[wid] = h; sc[wid] = c; sg[wid] = d; }
    __syncthreads();
    if (t == 0) {
        double Craw = sc[0] + sc[1] + sc[2] + sc[3];  // sum s*log2(s)
        // - sum s = -2*N^2 exactly; + eps linearization constant
        double corr = 2.0 * 1e-8 * (double)DD * (double)NN * (double)NN / LN2;
        double Ct = (Craw - 2.0 * (double)NN * (double)NN + corr) * LN2;
        double SH = (sh[0] + sh[1] + sh[2] + sh[3]) * LN2;
        double Cd = (sg[0] + sg[1] + sg[2] + sg[3]) * LN2;
        double diag_sum  = 0.5 * (SH - Cd);
        double total_sum = 0.5 * ((double)NN * SH - Ct);
        double pos = diag_sum / (double)NN;
        double neg = -(total_sum - diag_sum) / ((double)NN * (double)NN - (double)NN);
        out[0] = (float)(pos + neg);
    }
}

extern "C" void kernel_launch(void* const* d_in, const int* in_sizes, int n_in,
                              void* d_out, int out_size, void* d_ws, size_t ws_size,
                              hipStream_t stream) {
    const float* z1 = (const float*)d_in[0];
    const float* z2 = (const float*)d_in[1];
    char* ws = (char*)d_ws;
    double* hrow  = (double*)(ws);
    double* cpart = (double*)(ws + 8192);
    double* dpart = (double*)(ws + 24576);
    float*  p1    = (float*)(ws + 32768);
    float*  p2    = p1 + (size_t)NN * DD;
    float* out = (float*)d_out;

    k_softmax<<<2 * NN, THREADS, 0, stream>>>(z1, z2, p1, p2, hrow);
    k_cross<<<dim3(IBLK, JBLK + 1), THREADS, 0, stream>>>(p1, p2, cpart, dpart);
    k_final<<<1, 256, 0, stream>>>(hrow, cpart, dpart, out);
}

// Round 5
// 86.408 us; speedup vs baseline: 2.1649x; 1.0153x over previous
//
#include <hip/hip_runtime.h>

#define NN 512
#define DD 768
#define EPSF 1e-8f
#define TI 8
#define JCHUNK 16
#define JBLK (NN / JCHUNK)   // 32
#define IBLK (NN / TI)       // 64
#define THREADS 192
#define LN2 0.6931471805599453

// ws layout (bytes):
//   hrow  @ 0      : 1024 doubles (per-row H, log2 units)
//   cpart @ 8192   : IBLK*JBLK = 2048 doubles (cross partials, raw sum s*log2(s))
//   dpart @ 24576  : IBLK = 64 doubles (diag partials, exact-eps, log2 units)
//   p1    @ 32768  : 512*768 floats
//   p2    after p1
//
// Cross identity:  sum_d s*log2(s/2+eps)
//                = sum_d s*log2(s) - sum_d s + sum_d s*log2(1+2eps/s)
//   summed over all (i,j): sum s = 2*N^2 exactly; eps term -> 2*EPS*D*N^2/ln2.
//   Both folded into k_final analytically.

// One WAVE per row (rows 0..511 -> z1, 512..1023 -> z2). 12 elements/lane,
// shuffle-only reductions, no __syncthreads.
__global__ __launch_bounds__(256) void k_softmax(
    const float* __restrict__ z1, const float* __restrict__ z2,
    float* __restrict__ p1, float* __restrict__ p2, double* __restrict__ hrow) {
    int t = threadIdx.x;
    int lane = t & 63, w = t >> 6;
    int r = blockIdx.x * 4 + w;
    const float* z = (r < NN) ? (z1 + (size_t)r * DD) : (z2 + (size_t)(r - NN) * DD);
    float*       p = (r < NN) ? (p1 + (size_t)r * DD) : (p2 + (size_t)(r - NN) * DD);

    float4 v0 = *(const float4*)(z + 4 * lane);
    float4 v1 = *(const float4*)(z + 256 + 4 * lane);
    float4 v2 = *(const float4*)(z + 512 + 4 * lane);

    float m = fmaxf(fmaxf(fmaxf(v0.x, v0.y), fmaxf(v0.z, v0.w)),
             fmaxf(fmaxf(fmaxf(v1.x, v1.y), fmaxf(v1.z, v1.w)),
                   fmaxf(fmaxf(v2.x, v2.y), fmaxf(v2.z, v2.w))));
    #pragma unroll
    for (int o = 32; o; o >>= 1) m = fmaxf(m, __shfl_xor(m, o, 64));

    float4 e0, e1, e2;
    e0.x = __expf(v0.x - m); e0.y = __expf(v0.y - m); e0.z = __expf(v0.z - m); e0.w = __expf(v0.w - m);
    e1.x = __expf(v1.x - m); e1.y = __expf(v1.y - m); e1.z = __expf(v1.z - m); e1.w = __expf(v1.w - m);
    e2.x = __expf(v2.x - m); e2.y = __expf(v2.y - m); e2.z = __expf(v2.z - m); e2.w = __expf(v2.w - m);

    double s = ((double)e0.x + (double)e0.y) + ((double)e0.z + (double)e0.w)
             + ((double)e1.x + (double)e1.y) + ((double)e1.z + (double)e1.w)
             + ((double)e2.x + (double)e2.y) + ((double)e2.z + (double)e2.w);
    #pragma unroll
    for (int o = 32; o; o >>= 1) s += __shfl_xor(s, o, 64);
    float invS = 1.0f / (float)s;

    float4 q0, q1, q2;
    q0.x = e0.x * invS; q0.y = e0.y * invS; q0.z = e0.z * invS; q0.w = e0.w * invS;
    q1.x = e1.x * invS; q1.y = e1.y * invS; q1.z = e1.z * invS; q1.w = e1.w * invS;
    q2.x = e2.x * invS; q2.y = e2.y * invS; q2.z = e2.z * invS; q2.w = e2.w * invS;
    *(float4*)(p + 4 * lane) = q0;
    *(float4*)(p + 256 + 4 * lane) = q1;
    *(float4*)(p + 512 + 4 * lane) = q2;

    float hf = 0.0f;
    hf = fmaf(q0.x, __log2f(q0.x + EPSF), hf); hf = fmaf(q0.y, __log2f(q0.y + EPSF), hf);
    hf = fmaf(q0.z, __log2f(q0.z + EPSF), hf); hf = fmaf(q0.w, __log2f(q0.w + EPSF), hf);
    hf = fmaf(q1.x, __log2f(q1.x + EPSF), hf); hf = fmaf(q1.y, __log2f(q1.y + EPSF), hf);
    hf = fmaf(q1.z, __log2f(q1.z + EPSF), hf); hf = fmaf(q1.w, __log2f(q1.w + EPSF), hf);
    hf = fmaf(q2.x, __log2f(q2.x + EPSF), hf); hf = fmaf(q2.y, __log2f(q2.y + EPSF), hf);
    hf = fmaf(q2.z, __log2f(q2.z + EPSF), hf); hf = fmaf(q2.w, __log2f(q2.w + EPSF), hf);
    double h = (double)hf;
    #pragma unroll
    for (int o = 32; o; o >>= 1) h += __shfl_down(h, o, 64);
    if (lane == 0) hrow[r] = h;
}

// Cross partials: raw sum of s*log2(s). grid = (IBLK, JBLK+1); y==JBLK does the
// exact-eps diagonal. 4 independent f32 accumulators (one per float4 component)
// persist across the j-loop -> 4x shorter dependent-FMA chain, no per-j f64 ops.
__global__ __launch_bounds__(THREADS, 6) void k_cross(
    const float* __restrict__ p1, const float* __restrict__ p2,
    double* __restrict__ cpart, double* __restrict__ dpart) {
    __shared__ double sd[4];
    int t = threadIdx.x;
    int bx = blockIdx.x;
    int by = blockIdx.y;
    int lane = t & 63, wid = t >> 6;
    double accd = 0.0;

    if (by < JBLK) {
        const float* ap = p1 + (size_t)bx * TI * DD + 4 * t;
        float4 a0 = *(const float4*)(ap + 0 * DD);
        float4 a1 = *(const float4*)(ap + 1 * DD);
        float4 a2 = *(const float4*)(ap + 2 * DD);
        float4 a3 = *(const float4*)(ap + 3 * DD);
        float4 a4 = *(const float4*)(ap + 4 * DD);
        float4 a5 = *(const float4*)(ap + 5 * DD);
        float4 a6 = *(const float4*)(ap + 6 * DD);
        float4 a7 = *(const float4*)(ap + 7 * DD);

        float px = 0.0f, py = 0.0f, pz = 0.0f, pw = 0.0f;
        const float* bp = p2 + (size_t)by * JCHUNK * DD + 4 * t;
        float4 b = *(const float4*)bp;
        for (int j = 0; j < JCHUNK; ++j) {
            float4 bn = (j + 1 < JCHUNK) ? *(const float4*)(bp + (size_t)(j + 1) * DD) : b;
            #define ELT(A) { \
                float sx = A.x + b.x, sy = A.y + b.y, sz = A.z + b.z, sw = A.w + b.w; \
                px = fmaf(sx, __log2f(sx), px); \
                py = fmaf(sy, __log2f(sy), py); \
                pz = fmaf(sz, __log2f(sz), pz); \
                pw = fmaf(sw, __log2f(sw), pw); }
            ELT(a0) ELT(a1) ELT(a2) ELT(a3) ELT(a4) ELT(a5) ELT(a6) ELT(a7)
            #undef ELT
            b = bn;
        }
        accd = ((double)px + (double)py) + ((double)pz + (double)pw);
    } else {
        #pragma unroll
        for (int k = 0; k < TI; ++k) {
            int i = bx * TI + k;
            float4 a = *(const float4*)(p1 + (size_t)i * DD + 4 * t);
            float4 b = *(const float4*)(p2 + (size_t)i * DD + 4 * t);
            float sx = a.x + b.x, sy = a.y + b.y, sz = a.z + b.z, sw = a.w + b.w;
            float part = 0.0f;
            part = fmaf(sx, __log2f(fmaf(0.5f, sx, EPSF)), part);
            part = fmaf(sy, __log2f(fmaf(0.5f, sy, EPSF)), part);
            part = fmaf(sz, __log2f(fmaf(0.5f, sz, EPSF)), part);
            part = fmaf(sw, __log2f(fmaf(0.5f, sw, EPSF)), part);
            accd += (double)part;
        }
    }

    #pragma unroll
    for (int o = 32; o; o >>= 1) accd += __shfl_down(accd, o, 64);
    if (lane == 0) sd[wid] = accd;
    __syncthreads();
    if (t == 0) {
        double v = sd[0] + sd[1] + sd[2];
        if (by < JBLK) cpart[by * IBLK + bx] = v;
        else           dpart[bx] = v;
    }
}

__global__ __launch_bounds__(256) void k_final(
    const double* __restrict__ hrow, const double* __restrict__ cpart,
    const double* __restrict__ dpart, float* __restrict__ out) {
    __shared__ double sh[4], sc[4], sg[4];
    int t = threadIdx.x, lane = t & 63, wid = t >> 6;
    double h = 0.0, c = 0.0, d = 0.0;
    for (int i = t; i < 2 * NN; i += 256) h += hrow[i];
    for (int i = t; i < IBLK * JBLK; i += 256) c += cpart[i];
    if (t < IBLK) d = dpart[t];
    #pragma unroll
    for (int o = 32; o; o >>= 1) {
        h += __shfl_down(h, o, 64);
        c += __shfl_down(c, o, 64);
        d += __shfl_down(d, o, 64);
    }
    if (lane == 0) { sh[wid] = h; sc[wid] = c; sg[wid] = d; }
    __syncthreads();
    if (t == 0) {
        double Craw = sc[0] + sc[1] + sc[2] + sc[3];  // sum s*log2(s)
        double corr = 2.0 * 1e-8 * (double)DD * (double)NN * (double)NN / LN2;
        double Ct = (Craw - 2.0 * (double)NN * (double)NN + corr) * LN2;
        double SH = (sh[0] + sh[1] + sh[2] + sh[3]) * LN2;
        double Cd = (sg[0] + sg[1] + sg[2] + sg[3]) * LN2;
        double diag_sum  = 0.5 * (SH - Cd);
        double total_sum = 0.5 * ((double)NN * SH - Ct);
        double pos = diag_sum / (double)NN;
        double neg = -(total_sum - diag_sum) / ((double)NN * (double)NN - (double)NN);
        out[0] = (float)(pos + neg);
    }
}

extern "C" void kernel_launch(void* const* d_in, const int* in_sizes, int n_in,
                              void* d_out, int out_size, void* d_ws, size_t ws_size,
                              hipStream_t stream) {
    const float* z1 = (const float*)d_in[0];
    const float* z2 = (const float*)d_in[1];
    char* ws = (char*)d_ws;
    double* hrow  = (double*)(ws);
    double* cpart = (double*)(ws + 8192);
    double* dpart = (double*)(ws + 24576);
    float*  p1    = (float*)(ws + 32768);
    float*  p2    = p1 + (size_t)NN * DD;
    float* out = (float*)d_out;

    k_softmax<<<(2 * NN) / 4, 256, 0, stream>>>(z1, z2, p1, p2, hrow);
    k_cross<<<dim3(IBLK, JBLK + 1), THREADS, 0, stream>>>(p1, p2, cpart, dpart);
    k_final<<<1, 256, 0, stream>>>(hrow, cpart, dpart, out);
}